// Round 7
// baseline (203.049 us; speedup 1.0000x reference)
//
#include <hip/hip_runtime.h>

#define POOL 7
#define NCH 256
#define OUT_PER_BOX (NCH * POOL * POOL)   // 12544
#define PARTS 7
#define PART_SZ (OUT_PER_BOX / PARTS)     // 1792
#define ITERS (PART_SZ / 256)             // 7
#define CPB 16                            // channels per staged block
#define NGRP (NCH / CPB)                  // 16 staged blocks per box
#define LDSF 7680                         // region floats budget (30 KB) -> R*Wp <= 480

// ---------------------------------------------------------------------------
// Shared per-box geometry. MUST be bit-identical in both kernels (same exprs):
// t=6 => t7 == 1.0f exactly, so the extreme taps are (by1+h)*Hm1 / (bx1+w)*Hm1.
// ---------------------------------------------------------------------------
struct Geom {
    const float* fm;
    float by1, bx1, h, w, Hm1;
    int H, ymin, R, xmin, W, Wp;
};

__device__ __forceinline__ Geom box_geom(
    const float* __restrict__ boxes, int n,
    const float* p2, const float* p3, const float* p4, const float* p5)
{
    Geom g;
    g.by1 = boxes[n * 4 + 0];
    g.bx1 = boxes[n * 4 + 1];
    const float by2 = boxes[n * 4 + 2];
    const float bx2 = boxes[n * 4 + 3];
    g.h = by2 - g.by1;
    g.w = bx2 - g.bx1;
    const float lvlf = 4.0f + log2f(sqrtf(g.h * g.w) / 0.21875f);
    int lvl = (int)rintf(lvlf);           // round-half-even, matches jnp.round
    lvl = lvl < 2 ? 2 : (lvl > 5 ? 5 : lvl);
    switch (lvl) {
        case 2:  g.fm = p2; g.H = 256; break;
        case 3:  g.fm = p3; g.H = 128; break;
        case 4:  g.fm = p4; g.H = 64;  break;
        default: g.fm = p5; g.H = 32;  break;
    }
    g.Hm1 = (float)(g.H - 1);
    // sample-tap extremes (t=0 and t=6); taps are monotone in t (h,w >= 0)
    int ya = (int)floorf((g.by1 + g.h * 0.0f) * g.Hm1); ya = min(g.H - 1, max(0, ya));
    int yb = (int)floorf((g.by1 + g.h * 1.0f) * g.Hm1); yb = min(g.H - 1, max(0, yb));
    int xa = (int)floorf((g.bx1 + g.w * 0.0f) * g.Hm1); xa = min(g.H - 1, max(0, xa));
    int xc = (int)floorf((g.bx1 + g.w * 1.0f) * g.Hm1); xc = min(g.H - 1, max(0, xc));
    const int xba = min(xa, g.H - 2);
    const int xbb = min(xc, g.H - 2);
    g.ymin = ya;
    g.R    = min(g.H - 1, yb + 1) - ya + 1;   // rows [ymin, y1max]
    g.xmin = xba;
    g.W    = xbb + 2 - xba;                   // cols [xmin, xbb+1]
    g.Wp   = g.W | 1;                         // odd pitch: no 32-bank alignment
    return g;
}

__device__ __forceinline__ unsigned magic_of(int d) {   // exact q/d for q,d < 2^14
    return (unsigned)((0x100000000ULL + (unsigned)d - 1) / (unsigned)d);
}
__device__ __forceinline__ unsigned magic_div(unsigned q, unsigned m) {
    return (unsigned)(((unsigned long long)q * m) >> 32);
}

// ---------------------------------------------------------------------------
// Staged kernel: block = (box, 16-channel group). Stage the box's own bbox
// region for its channels with COALESCED loads (consecutive lanes =
// consecutive columns), one barrier, bilinear-sample from LDS, coalesced
// stores. Handles boxes with R*Wp <= 480 (~85%).
// ---------------------------------------------------------------------------
__global__ __launch_bounds__(256) void staged_kernel(
    const float* __restrict__ boxes,
    const float* __restrict__ p2, const float* __restrict__ p3,
    const float* __restrict__ p4, const float* __restrict__ p5,
    float* __restrict__ out, int nbox)
{
    __shared__ float reg[LDSF];
    __shared__ int   s_y0[POOL], s_y1[POOL], s_xb[POOL], s_xcl[POOL];
    __shared__ float s_wy[POOL], s_wx[POOL], s_vy[POOL], s_vx[POOL];

    const int bid = blockIdx.x;
    const int n   = bid / NGRP;
    const int gr  = bid - n * NGRP;
    const Geom g = box_geom(boxes, n, p2, p3, p4, p5);
    if (CPB * g.R * g.Wp > LDSF) return;      // gather kernel handles it

    const int tid = threadIdx.x;
    const int H = g.H, HW = g.H * g.H;
    const float Hm1 = g.Hm1;

    if (tid < POOL) {
        const float t7 = (float)tid * (1.0f / 6.0f);
        const float yy  = (g.by1 + g.h * t7) * Hm1;
        const float y0f = floorf(yy);
        int y0 = (int)y0f; y0 = min(H - 1, max(0, y0));
        s_y0[tid] = y0;
        s_y1[tid] = min(H - 1, y0 + 1);
        s_wy[tid] = yy - y0f;                 // weight from UNCLIPPED floor
        s_vy[tid] = (yy >= 0.0f && yy <= Hm1) ? 1.0f : 0.0f;

        const float xx  = (g.bx1 + g.w * t7) * Hm1;
        const float x0f = floorf(xx);
        int x0 = (int)x0f; x0 = min(H - 1, max(0, x0));
        s_xb[tid]  = min(x0, H - 2);
        s_xcl[tid] = (x0 == H - 1) ? 1 : 0;
        s_wx[tid]  = xx - x0f;
        s_vx[tid]  = (xx >= 0.0f && xx <= Hm1) ? 1.0f : 0.0f;
    }

    // ---- stage CPB channel regions (coalesced: col fastest) ----
    const int c0  = gr * CPB;
    const int RW  = g.R * g.W;
    const int tot = CPB * RW;
    const unsigned mRW = magic_of(RW);
    const unsigned mW  = magic_of(g.W);
    const float* fmbase = g.fm + (size_t)c0 * HW + g.ymin * H + g.xmin;
    for (int q = tid; q < tot; q += 256) {
        const int ch  = (int)magic_div((unsigned)q, mRW);
        const int rem = q - ch * RW;
        const int r   = (int)magic_div((unsigned)rem, mW);
        const int col = rem - r * g.W;
        reg[ch * (g.R * g.Wp) + r * g.Wp + col] =
            fmbase[(size_t)ch * HW + r * H + col];
    }
    __syncthreads();

    // ---- sample 16 channels x 49 positions from LDS ----
    const size_t ob = (size_t)n * OUT_PER_BOX + (size_t)c0 * 49;
    #pragma unroll
    for (int i0 = 0; i0 < CPB * 49; i0 += 256) {
        const int i = i0 + tid;
        if (i < CPB * 49) {
            const int cl  = i / 49;           // compile-time divisors
            const int pos = i - cl * 49;
            const int py  = pos / 7;
            const int px  = pos - py * 7;

            const float* base = &reg[cl * (g.R * g.Wp)];
            const int r0  = s_y0[py] - g.ymin;
            const int r1  = s_y1[py] - g.ymin;
            const int xo  = s_xb[px] - g.xmin;
            const int clx = s_xcl[px];

            const float v00 = base[r0 * g.Wp + xo + clx];
            const float v01 = base[r0 * g.Wp + xo + 1];
            const float v10 = base[r1 * g.Wp + xo + clx];
            const float v11 = base[r1 * g.Wp + xo + 1];

            const float wy = s_wy[py], wx = s_wx[px];
            const float a0 = v00 + wx * (v01 - v00);
            const float a1 = v10 + wx * (v11 - v10);
            out[ob + i] = (a0 + wy * (a1 - a0)) * s_vy[py] * s_vx[px];
        }
    }
}

// ---------------------------------------------------------------------------
// Gather kernel: verified R0 body, 512 B LDS, full occupancy. Handles the
// big boxes (R*Wp > 480: most level-2, fat level-3/4).
// ---------------------------------------------------------------------------
__global__ __launch_bounds__(256) void gather_kernel(
    const float* __restrict__ boxes,
    const float* __restrict__ p2, const float* __restrict__ p3,
    const float* __restrict__ p4, const float* __restrict__ p5,
    float* __restrict__ out, int nbox)
{
    const int n    = blockIdx.x % nbox;
    const int part = blockIdx.x / nbox;
    const Geom g = box_geom(boxes, n, p2, p3, p4, p5);
    if (CPB * g.R * g.Wp <= LDSF) return;     // staged kernel handles it

    __shared__ int   s_y0[POOL], s_y1[POOL], s_xb[POOL], s_xcl[POOL];
    __shared__ float s_wy[POOL], s_wx[POOL], s_vy[POOL], s_vx[POOL];

    const int tid = threadIdx.x;
    const int H = g.H, HW = g.H * g.H;
    const float Hm1 = g.Hm1;
    const float* fm = g.fm;

    if (tid < POOL) {
        const float t7 = (float)tid * (1.0f / 6.0f);
        const float yy  = (g.by1 + g.h * t7) * Hm1;
        const float y0f = floorf(yy);
        int y0 = (int)y0f; y0 = min(H - 1, max(0, y0));
        s_y0[tid] = y0;
        s_y1[tid] = min(H - 1, y0 + 1);
        s_wy[tid] = yy - y0f;
        s_vy[tid] = (yy >= 0.0f && yy <= Hm1) ? 1.0f : 0.0f;

        const float xx  = (g.bx1 + g.w * t7) * Hm1;
        const float x0f = floorf(xx);
        int x0 = (int)x0f; x0 = min(H - 1, max(0, x0));
        s_xb[tid]  = min(x0, H - 2);
        s_xcl[tid] = (x0 == H - 1) ? 1 : 0;
        s_wx[tid]  = xx - x0f;
        s_vx[tid]  = (xx >= 0.0f && xx <= Hm1) ? 1.0f : 0.0f;
    }
    __syncthreads();

    const size_t out_base = (size_t)n * OUT_PER_BOX + (size_t)part * PART_SZ;
    const int idx0 = part * PART_SZ + tid;

    float2 q0[ITERS], q1[ITERS];
    #pragma unroll
    for (int i = 0; i < ITERS; ++i) {
        const int idx = idx0 + i * 256;
        const int c  = idx / 49;
        const int r  = idx - c * 49;
        const int py = r / 7;
        const int px = r - py * 7;
        const float* fmc = fm + (size_t)c * HW;
        const int xb = s_xb[px];
        q0[i] = *(const float2*)(fmc + s_y0[py] * H + xb);
        q1[i] = *(const float2*)(fmc + s_y1[py] * H + xb);
    }
    #pragma unroll
    for (int i = 0; i < ITERS; ++i) {
        const int idx = idx0 + i * 256;
        const int c  = idx / 49;
        const int r  = idx - c * 49;
        const int py = r / 7;
        const int px = r - py * 7;
        const float wy = s_wy[py], wx = s_wx[px];
        const int   cl = s_xcl[px];
        const float v00 = cl ? q0[i].y : q0[i].x;
        const float v01 = q0[i].y;
        const float v10 = cl ? q1[i].y : q1[i].x;
        const float v11 = q1[i].y;
        const float r0 = v00 + wx * (v01 - v00);
        const float r1 = v10 + wx * (v11 - v10);
        out[out_base + (size_t)(i * 256 + tid)] =
            (r0 + wy * (r1 - r0)) * s_vy[py] * s_vx[px];
    }
}

extern "C" void kernel_launch(void* const* d_in, const int* in_sizes, int n_in,
                              void* d_out, int out_size, void* d_ws, size_t ws_size,
                              hipStream_t stream) {
    const float* boxes = (const float*)d_in[0];
    const float* p2    = (const float*)d_in[1];
    const float* p3    = (const float*)d_in[2];
    const float* p4    = (const float*)d_in[3];
    const float* p5    = (const float*)d_in[4];
    float* out         = (float*)d_out;

    const int nbox = in_sizes[0] / 4;   // 1000

    staged_kernel<<<nbox * NGRP, 256, 0, stream>>>(
        boxes, p2, p3, p4, p5, out, nbox);
    gather_kernel<<<nbox * PARTS, 256, 0, stream>>>(
        boxes, p2, p3, p4, p5, out, nbox);
}

// Round 8
// 154.903 us; speedup vs baseline: 1.3108x; 1.3108x over previous
//
#include <hip/hip_runtime.h>

#define POOL 7
#define NCH 256
#define OUT_PER_BOX (NCH * POOL * POOL)   // 12544 = 7 * 1792
#define PARTS 7
#define PART_SZ (OUT_PER_BOX / PARTS)     // 1792 = 7 * 256
#define ITERS (PART_SZ / 256)             // 7
#define NXCD 8
#define CHB 8                              // boxes per deal-chunk
#define CHU (CHB * PARTS)                  // 56 work-units per chunk (box-aligned)
#define GRPU (NXCD * CHU)                  // 448 work-units per deal round

// ---------------------------------------------------------------------------
// Kernel 1: counting sort of boxes into 64 bins = (level, 4x4 spatial quadrant).
// Order within a bin is arbitrary (atomic scatter) — output is indexed by the
// ORIGINAL box id, so perm order only affects the schedule, not correctness.
// ---------------------------------------------------------------------------
#define NBINS 64

__global__ __launch_bounds__(1024) void bin_boxes_kernel(
    const float* __restrict__ boxes, int* __restrict__ perm, int nbox)
{
    __shared__ int s_cnt[NBINS];
    __shared__ int s_off[NBINS];
    const int i = threadIdx.x;

    if (i < NBINS) s_cnt[i] = 0;
    __syncthreads();

    int bin = -1;
    if (i < nbox) {
        const float y1 = boxes[i * 4 + 0];
        const float x1 = boxes[i * 4 + 1];
        const float y2 = boxes[i * 4 + 2];
        const float x2 = boxes[i * 4 + 3];
        const float h = y2 - y1;
        const float w = x2 - x1;
        const float lvlf = 4.0f + log2f(sqrtf(h * w) * (1.0f / 0.21875f));
        int lvl = (int)rintf(lvlf);
        lvl = lvl < 2 ? 2 : (lvl > 5 ? 5 : lvl);
        const float cy = 0.5f * (y1 + y2);
        const float cx = 0.5f * (x1 + x2);
        int qy = (int)(cy * 4.0f); qy = qy < 0 ? 0 : (qy > 3 ? 3 : qy);
        int qx = (int)(cx * 4.0f); qx = qx < 0 ? 0 : (qx > 3 ? 3 : qx);
        bin = ((lvl - 2) << 4) | (qy << 2) | qx;
        atomicAdd(&s_cnt[bin], 1);
    }
    __syncthreads();

    if (i == 0) {
        int acc = 0;
        for (int b = 0; b < NBINS; ++b) { s_off[b] = acc; acc += s_cnt[b]; }
    }
    __syncthreads();

    if (i < nbox) {
        const int pos = atomicAdd(&s_off[bin], 1);
        perm[pos] = i;
    }
}

// Fallback for nbox > 1024 (never hit with this harness): identity perm.
__global__ void identity_perm_kernel(int* __restrict__ perm, int nbox) {
    const int i = blockIdx.x * blockDim.x + threadIdx.x;
    if (i < nbox) perm[i] = i;
}

// ---------------------------------------------------------------------------
// Kernel 2: ROI-align. Body identical to the verified round-0/round-2 kernel.
// Mapping: sorted boxes dealt to XCDs in 8-box chunks (R2 schedule: balanced
// + partial locality, best measured = 50 us).
// SINGLE CHANGE THIS ROUND: __launch_bounds__(256, 8) — request 8 waves/EU
// (= 32 waves/CU = 8 blocks/CU; VGPR=28 and LDS=512B both permit it).
// Occupancy probe: latency-bound -> time drops; miss-throughput-bound ->
// occupancy rises but time flat.
// ---------------------------------------------------------------------------
__global__ __launch_bounds__(256, 8) void roi_align_kernel(
    const float* __restrict__ boxes,
    const float* __restrict__ p2,
    const float* __restrict__ p3,
    const float* __restrict__ p4,
    const float* __restrict__ p5,
    float* __restrict__ out,
    const int* __restrict__ perm,
    int nbox, int total_u)
{
    const int xcd    = blockIdx.x & (NXCD - 1);
    const int t      = blockIdx.x >> 3;
    const int grp    = t / CHU;
    const int within = t - grp * CHU;
    const int u      = grp * GRPU + xcd * CHU + within;   // bijective over padded grid
    if (u >= total_u) return;
    const int s    = u / PARTS;
    const int part = u - s * PARTS;
    const int n    = perm[s];
    const int tid  = threadIdx.x;

    __shared__ int   s_y0[POOL], s_y1[POOL], s_xb[POOL], s_xcl[POOL];
    __shared__ float s_wy[POOL], s_wx[POOL], s_vy[POOL], s_vx[POOL];

    const float by1 = boxes[n * 4 + 0];
    const float bx1 = boxes[n * 4 + 1];
    const float by2 = boxes[n * 4 + 2];
    const float bx2 = boxes[n * 4 + 3];
    const float h = by2 - by1;
    const float w = bx2 - bx1;

    // roi_level = clip(round(4 + log2(sqrt(h*w) / (224/1024))), 2, 5)
    const float lvlf = 4.0f + log2f(sqrtf(h * w) / 0.21875f);
    int lvl = (int)rintf(lvlf);          // round-half-to-even, matches jnp.round
    lvl = lvl < 2 ? 2 : (lvl > 5 ? 5 : lvl);

    const float* fm;
    int H;
    switch (lvl) {
        case 2:  fm = p2; H = 256; break;
        case 3:  fm = p3; H = 128; break;
        case 4:  fm = p4; H = 64;  break;
        default: fm = p5; H = 32;  break;
    }
    const float Hm1 = (float)(H - 1);

    if (tid < POOL) {
        const float t7 = (float)tid * (1.0f / 6.0f);

        const float yy  = (by1 + h * t7) * Hm1;
        const float y0f = floorf(yy);
        int y0 = (int)y0f;
        y0 = min(H - 1, max(0, y0));
        s_y0[tid] = y0;
        s_y1[tid] = min(H - 1, y0 + 1);
        s_wy[tid] = yy - y0f;                       // weight from UNCLIPPED floor
        s_vy[tid] = (yy >= 0.0f && yy <= Hm1) ? 1.0f : 0.0f;

        const float xx  = (bx1 + w * t7) * Hm1;
        const float x0f = floorf(xx);
        int x0 = (int)x0f;
        x0 = min(H - 1, max(0, x0));
        // paired-load base: float2 at xb covers {xb, xb+1}.
        //   x0 <= H-2 : v00 = pair.x, v01 = pair.y   (x1 = x0+1)
        //   x0 == H-1 : v00 = v01 = pair.y           (x1 = x0, clamped)
        s_xb[tid]  = min(x0, H - 2);
        s_xcl[tid] = (x0 == H - 1) ? 1 : 0;
        s_wx[tid]  = xx - x0f;
        s_vx[tid]  = (xx >= 0.0f && xx <= Hm1) ? 1.0f : 0.0f;
    }
    __syncthreads();

    const size_t out_base = (size_t)n * OUT_PER_BOX + (size_t)part * PART_SZ;
    const int idx0 = part * PART_SZ + tid;
    const int HW = H * H;

    // Phase 1: issue all 14 dwordx2 gathers, keep results in registers.
    float2 q0[ITERS], q1[ITERS];
    #pragma unroll
    for (int i = 0; i < ITERS; ++i) {
        const int idx = idx0 + i * 256;
        const int cch = idx / 49;
        const int r   = idx - cch * 49;
        const int py  = r / 7;
        const int px  = r - py * 7;

        const float* fmc = fm + (size_t)cch * HW;
        const int xb = s_xb[px];
        q0[i] = *(const float2*)(fmc + s_y0[py] * H + xb);
        q1[i] = *(const float2*)(fmc + s_y1[py] * H + xb);
    }

    // Phase 2: lerp + store (coalesced).
    #pragma unroll
    for (int i = 0; i < ITERS; ++i) {
        const int idx = idx0 + i * 256;
        const int cch = idx / 49;
        const int r   = idx - cch * 49;
        const int py  = r / 7;
        const int px  = r - py * 7;

        const float wy = s_wy[py], wx = s_wx[px];
        const int   cl = s_xcl[px];

        const float v00 = cl ? q0[i].y : q0[i].x;
        const float v01 = q0[i].y;
        const float v10 = cl ? q1[i].y : q1[i].x;
        const float v11 = q1[i].y;

        const float r0 = v00 + wx * (v01 - v00);
        const float r1 = v10 + wx * (v11 - v10);
        float val = (r0 + wy * (r1 - r0)) * s_vy[py] * s_vx[px];

        out[out_base + (size_t)(i * 256 + tid)] = val;
    }
}

extern "C" void kernel_launch(void* const* d_in, const int* in_sizes, int n_in,
                              void* d_out, int out_size, void* d_ws, size_t ws_size,
                              hipStream_t stream) {
    const float* boxes = (const float*)d_in[0];
    const float* p2    = (const float*)d_in[1];
    const float* p3    = (const float*)d_in[2];
    const float* p4    = (const float*)d_in[3];
    const float* p5    = (const float*)d_in[4];
    float* out         = (float*)d_out;
    int*   perm        = (int*)d_ws;

    const int nbox    = in_sizes[0] / 4;        // 1000
    const int total_u = nbox * PARTS;           // 7000
    const int grid    = ((total_u + GRPU - 1) / GRPU) * GRPU;   // pad to 448 -> 7168

    if (nbox <= 1024) {
        bin_boxes_kernel<<<1, 1024, 0, stream>>>(boxes, perm, nbox);
    } else {
        identity_perm_kernel<<<(nbox + 255) / 256, 256, 0, stream>>>(perm, nbox);
    }

    roi_align_kernel<<<grid, 256, 0, stream>>>(
        boxes, p2, p3, p4, p5, out, perm, nbox, total_u);
}